// Round 3
// baseline (173.006 us; speedup 1.0000x reference)
//
#include <hip/hip_runtime.h>
#include <math.h>

#define TILE_W 64
#define TILE_H 4
#define HALO 4
#define TWX 72
#define TWY 12
#define NST (TWX*TWY)   // 864
#define QIW 528         // quad image row stride (float4 elems)
#define QIH 520

#if __has_builtin(__builtin_amdgcn_fractf)
#define FRACTF(x) __builtin_amdgcn_fractf(x)
#else
#define FRACTF(x) ((x) - floorf(x))
#endif
#if __has_builtin(__builtin_amdgcn_exp2f)
#define EXP2F(x) __builtin_amdgcn_exp2f(x)
#else
#define EXP2F(x) exp2f(x)
#endif
#if __has_builtin(__builtin_amdgcn_logf)
#define LOG2F(x) __builtin_amdgcn_logf(x)
#else
#define LOG2F(x) log2f(x)
#endif

// tbl layout (floats):
// [0..23] cos_q  [24..47] sin_q  [48..71] cos_q*SC  [72..95] sin_q*SC
// [96..103] wn_norm*log2e  [104] irt*log2e  [105] gamma  [106] gain
// [107] dense flag (int)  [108..139] sparse tap w [4][8]  [140..171] sparse tap off (int)
// [172] fastconv ok flag (int)  [180..183] per-bank equal weight
__global__ __launch_bounds__(64) void gp_setup(const float* __restrict__ gain,
                                               const float* __restrict__ lrt,
                                               const float* __restrict__ rlg,
                                               const float* __restrict__ Wb,
                                               float* __restrict__ tbl) {
  int t = threadIdx.x;
  __shared__ float wtmp[8];
  if (t < 8) {
    float tn = (float)(t + 1) * 0.375f;
    wtmp[t] = expf(-0.5f * tn * tn);
  }
  if (t < 24) {
    float th = (6.283185307179586f * (float)t) / 24.0f;
    float c = cosf(th), s = sinf(th);
    const float sc = (float)(512.0 / 511.0);
    tbl[t] = c; tbl[24 + t] = s; tbl[48 + t] = c * sc; tbl[72 + t] = s * sc;
  }
  __syncthreads();
  if (t == 0) {
    const float L2E = 1.44269504088896340736f;
    float sum = 0.f;
    for (int n = 0; n < 8; ++n) sum += wtmp[n];
    for (int n = 0; n < 8; ++n) tbl[96 + n] = (wtmp[n] / sum) * L2E;
    float rt = expf(lrt[0]);
    rt = fminf(fmaxf(rt, 0.001f), 2.0f);
    float sg = 1.0f / (1.0f + expf(-rlg[0]));
    float rho = sg * 0.95f + 0.05f;
    tbl[104] = (1.0f / rt) * L2E;
    tbl[105] = 1.0f / (rho + 1e-8f);
    tbl[106] = fmaxf(gain[0], 0.001f);

    int* ti = (int*)tbl;
    // sparse tap extraction (fallback kernel)
    int dense = 0;
    for (int o = 0; o < 4; ++o) {
      int cnt = 0;
      for (int k = 0; k < 49; ++k) {
        float w = Wb[o * 49 + k];
        if (w != 0.0f) {
          if (cnt < 8) {
            int kj = k / 7, ki = k - kj * 7;
            tbl[108 + o * 8 + cnt] = w;
            ti[140 + o * 8 + cnt] = kj * TWX + ki;
          }
          cnt++;
        }
      }
      if (cnt > 8) dense = 1;
      for (int c2 = cnt; c2 < 8; ++c2) { tbl[108 + o * 8 + c2] = 0.f; ti[140 + o * 8 + c2] = 0; }
    }
    ti[107] = dense;

    // fast-conv verification: expected line-mask pattern (n=4, tol=0.5) +
    // all-equal weights. Derived offline; verified here at runtime.
    const int K0[7] = {14,15,23,24,25,33,34};
    const int K1[7] = {2,9,17,24,31,39,46};
    const int K2[7] = {4,11,17,24,31,37,44};
    const int K3[7] = {19,20,23,24,25,28,29};
    const int* KK[4] = {K0,K1,K2,K3};
    int ok = 1;
    for (int o = 0; o < 4; ++o) {
      float w0v = Wb[o * 49 + KK[o][0]];
      if (w0v == 0.f) ok = 0;
      unsigned long long mask = 0;
      for (int t2 = 0; t2 < 7; ++t2) mask |= 1ull << KK[o][t2];
      for (int k = 0; k < 49; ++k) {
        float w = Wb[o * 49 + k];
        int nz = (w != 0.f);
        int want = (int)((mask >> k) & 1ull);
        if (nz != want) ok = 0;
        if (nz && w != w0v) ok = 0;
      }
      tbl[180 + o] = w0v;
    }
    ti[172] = ok;
  }
}

__device__ inline float fmv(const float* __restrict__ x0p, const float* __restrict__ x1p,
                            int Y, int X) {
  if ((unsigned)X < 512u && (unsigned)Y < 512u) {
    size_t o = (size_t)Y * 512 + X;
    float a = x0p[o], b = x1p[o];
    return sqrtf(a * a + b * b);
  }
  return 0.f;
}

// Prepass: pre-differenced bilinear quads with 4px zero halo.
// Q = (v00, v01-v00, v10-v00, v11-v10-v01+v00) -> bilinear = 1 mul + 3 fma.
__global__ __launch_bounds__(256) void gp_quad(const float* __restrict__ x,
                                               float4* __restrict__ qimg) {
  int xx = blockIdx.x * 64 + (threadIdx.x & 63);
  int yy = blockIdx.y * 4 + (threadIdx.x >> 6);
  int b = blockIdx.z;
  if (xx >= QIH) return;
  const float* x0p = x + (size_t)b * 2 * 512 * 512;
  const float* x1p = x0p + 512 * 512;
  int X = xx - 4, Y = yy - 4;
  float f00 = fmv(x0p, x1p, Y, X);
  float f01 = fmv(x0p, x1p, Y, X + 1);
  float f10 = fmv(x0p, x1p, Y + 1, X);
  float f11 = fmv(x0p, x1p, Y + 1, X + 1);
  qimg[((size_t)b * QIH + yy) * QIW + xx] =
      make_float4(f00, f01 - f00, f10 - f00, (f11 - f10) - (f01 - f00));
}

// Main: 4/8 radii sampled from LDS tile, 4/8 from the quad image via the
// (otherwise idle) vector-memory pipe. XCD swizzle: each XCD owns one batch
// image (4.4MB ~ its private L2).
__global__ __launch_bounds__(256) void gp_main2(const float* __restrict__ x,
                                                const float4* __restrict__ qimg,
                                                const float* __restrict__ Wb,
                                                const float* __restrict__ cen,
                                                const float* __restrict__ tbl,
                                                float* __restrict__ out) {
  __shared__ float4 Qd[1024];   // window 12x72 + pad (staging convenience)
  __shared__ float  Sm[NST];

  const int tid = threadIdx.x;
  const int tx = tid & 63, ty = tid >> 6;
  int wg = blockIdx.x;
  int swz = (wg & 7) * 1024 + (wg >> 3);   // XCD k -> contiguous chunk = batch k
  int bx = swz & 7;
  int by = (swz >> 3) & 127;
  int b  = swz >> 10;

  const int bx0 = bx * 64 - HALO, by0 = by * 4 - HALO;
  const float* __restrict__ x0p = x + (size_t)b * 2 * 512 * 512;
  const float* __restrict__ x1p = x0p + 512 * 512;
  const float4* __restrict__ qb = qimg + ((size_t)b * QIH + (by * 4)) * QIW + (bx * 64);

  // Stage quad window (plain b128 copy) and Sm = x0+x1 (zero halo).
  #pragma unroll
  for (int it = 0; it < 4; ++it) {
    int idx = tid + it * 256;
    int i2 = (idx < NST) ? idx : (NST - 1);
    int r = i2 / TWX, c = i2 - r * TWX;
    Qd[idx] = qb[r * QIW + c];
  }
  #pragma unroll
  for (int it = 0; it < 4; ++it) {
    int idx = tid + it * 256;
    if (idx < NST) {
      int r = idx / TWX, c = idx - r * TWX;
      int gy = by0 + r, gx = bx0 + c;
      float a = 0.f, bv = 0.f;
      if ((unsigned)gx < 512u && (unsigned)gy < 512u) {
        size_t o = (size_t)gy * 512 + gx;
        a = x0p[o]; bv = x1p[o];
      }
      Sm[idx] = a + bv;
    }
  }
  __syncthreads();

  const int gi = bx * 64 + tx;
  const int gj = by * 4 + ty;
  const float SC = (float)(512.0 / 511.0);
  const float axl = fmaf((float)gi, SC, -0.5f) - (float)bx0;  // window coords, >0
  const float ayl = fmaf((float)gj, SC, -0.5f) - (float)by0;

  float wn[8];
  #pragma unroll
  for (int n = 0; n < 8; ++n) wn[n] = tbl[96 + n];

  float SY = 0.f, CX = 0.f;
  for (int q = 0; q < 24; ++q) {
    const float csx = tbl[48 + q];
    const float ssy = tbl[72 + q];
    // odd radii via vector-memory pipe (issue loads early)
    float4 vm[4]; float fxs[4], fys[4];
    #pragma unroll
    for (int h = 0; h < 4; ++h) {
      float tn = 0.75f * (float)(h + 1);          // t for n = 2h+1
      float px = fmaf(-csx, tn, axl);
      float py = fmaf(-ssy, tn, ayl);
      int ix = (int)px, iy = (int)py;
      fxs[h] = FRACTF(px); fys[h] = FRACTF(py);
      vm[h] = qb[iy * QIW + ix];
    }
    float e2 = 0.f;
    #pragma unroll
    for (int n = 0; n < 8; ++n) {
      float s;
      if (n & 1) {
        int h = n >> 1;
        float4 v = vm[h];
        float fx = fxs[h], fy = fys[h];
        s = fmaf(fx * fy, v.w, fmaf(fy, v.z, fmaf(fx, v.y, v.x)));
      } else {
        float tn = 0.375f * (float)(n + 1);
        float px = fmaf(-csx, tn, axl);
        float py = fmaf(-ssy, tn, ayl);
        int ix = (int)px, iy = (int)py;
        float fx = FRACTF(px), fy = FRACTF(py);
        float4 v = Qd[iy * TWX + ix];
        s = fmaf(fx * fy, v.w, fmaf(fy, v.z, fmaf(fx, v.y, v.x)));
      }
      e2 = fmaf(wn[n], s, e2);   // fold in n order (bit-stable vs R2)
    }
    float e = EXP2F(e2);
    SY = fmaf(e, tbl[24 + q], SY);
    CX = fmaf(e, tbl[q], CX);
  }

  // Conv: verified line-mask fast path (equal weights, shared center triples).
  const int* ti = (const int*)tbl;
  const int ccen = (ty + 4) * TWX + tx + 4;
  float a0, a1, a2, a3;
  if (ti[172]) {
    float sCt = Sm[ccen];
    float H3 = (Sm[ccen - 1] + sCt) + Sm[ccen + 1];
    float V3 = (Sm[ccen - TWX] + sCt) + Sm[ccen + TWX];
    a0 = tbl[180] * (H3 + ((Sm[ccen - 75] + Sm[ccen - 74]) + (Sm[ccen + 74] + Sm[ccen + 75])));
    a1 = tbl[181] * (V3 + ((Sm[ccen - 217] + Sm[ccen - 145]) + (Sm[ccen + 145] + Sm[ccen + 217])));
    a2 = tbl[182] * (V3 + ((Sm[ccen - 215] + Sm[ccen - 143]) + (Sm[ccen + 143] + Sm[ccen + 215])));
    a3 = tbl[183] * (H3 + ((Sm[ccen - 70] + Sm[ccen - 69]) + (Sm[ccen + 69] + Sm[ccen + 70])));
  } else {
    a0 = a1 = a2 = a3 = 0.f;
    for (int kj = 0; kj < 7; ++kj)
      for (int ki = 0; ki < 7; ++ki) {
        float s = Sm[(ty + 1 + kj) * TWX + (tx + 1 + ki)];
        int k = kj * 7 + ki;
        a0 = fmaf(s, Wb[k], a0); a1 = fmaf(s, Wb[49 + k], a1);
        a2 = fmaf(s, Wb[98 + k], a2); a3 = fmaf(s, Wb[147 + k], a3);
      }
  }

  const float TP  = 6.283185307179586f;
  const float PIF = 3.14159265358979323846f;
  const float HP  = 1.57079632679489661923f;
  float hat = atan2f(SY, CX);
  float r1 = hat + TP;
  r1 = (r1 >= TP) ? (r1 - TP) : r1;
  float theta = (r1 >= PIF) ? (r1 - PIF) : r1;

  const float irt2  = tbl[104];
  const float gamma = tbl[105];
  const float gainc = tbl[106];

  float dist[4];
  #pragma unroll
  for (int o = 0; o < 4; ++o) {
    float d = theta - cen[o] + HP;
    d -= (d >= PIF) ? PIF : 0.f;
    d += (d < 0.f) ? PIF : 0.f;
    dist[o] = fabsf(d - HP);
  }
  float mn = fminf(fminf(dist[0], dist[1]), fminf(dist[2], dist[3]));
  float m2 = mn * irt2;
  float eo[4], Z = 0.f;
  #pragma unroll
  for (int o = 0; o < 4; ++o) { eo[o] = EXP2F(fmaf(-irt2, dist[o], m2)); Z += eo[o]; }
  float invZ = 1.0f / Z;
  float sh[4], Zs = 0.f;
  #pragma unroll
  for (int o = 0; o < 4; ++o) {
    sh[o] = EXP2F(gamma * LOG2F(fmaf(eo[o], invZ, 1e-12f)));
    Zs += sh[o];
  }
  float wsi = 1.0f / (Zs + 1e-8f);
  float ov = (a0 * sh[0] + a1 * sh[1] + a2 * sh[2] + a3 * sh[3]) * wsi;

  out[((size_t)b * 512 + gj) * 512 + gi] = gainc * ov;
}

// Fallback (ws too small): Round-2 kernel verbatim (proven 146us path).
__global__ __launch_bounds__(256) void gp_main_fb(const float* __restrict__ x,
                                                  const float* __restrict__ Wb,
                                                  const float* __restrict__ cen,
                                                  const float* __restrict__ tbl,
                                                  float* __restrict__ out) {
  __shared__ float  Fm[NST];
  __shared__ float  Sm[NST];
  __shared__ float4 Qd[NST];
  const int tx = threadIdx.x;
  const int ty = threadIdx.y;
  const int tid = ty * 64 + tx;
  const int bx0 = blockIdx.x * TILE_W - HALO;
  const int by0 = blockIdx.y * TILE_H - HALO;
  const int b = blockIdx.z;
  const float* __restrict__ x0p = x + (size_t)b * 2 * 512 * 512;
  const float* __restrict__ x1p = x0p + 512 * 512;
  #pragma unroll
  for (int it = 0; it < 4; ++it) {
    int idx = tid + it * 256;
    if (idx < NST) {
      int r = idx / TWX, c = idx - r * TWX;
      int gy = by0 + r, gx = bx0 + c;
      float a = 0.f, bv = 0.f;
      if ((unsigned)gx < 512u && (unsigned)gy < 512u) {
        size_t o = (size_t)gy * 512 + gx;
        a = x0p[o]; bv = x1p[o];
      }
      Fm[idx] = sqrtf(a * a + bv * bv);
      Sm[idx] = a + bv;
    }
  }
  __syncthreads();
  #pragma unroll
  for (int it = 0; it < 4; ++it) {
    int idx = tid + it * 256;
    if (idx < NST) {
      int r = idx / TWX, c = idx - r * TWX;
      int r1 = (r < TWY - 1) ? r + 1 : r;
      int c1 = (c < TWX - 1) ? c + 1 : c;
      float v00 = Fm[r * TWX + c],  v01 = Fm[r * TWX + c1];
      float v10 = Fm[r1 * TWX + c], v11 = Fm[r1 * TWX + c1];
      Qd[idx] = make_float4(v00, v01 - v00, v10 - v00, (v11 - v10) - (v01 - v00));
    }
  }
  __syncthreads();
  const int gi = bx0 + HALO + tx;
  const int gj = by0 + HALO + ty;
  const float SC = (float)(512.0 / 511.0);
  const float axl = fmaf((float)gi, SC, -0.5f) - (float)bx0;
  const float ayl = fmaf((float)gj, SC, -0.5f) - (float)by0;
  float wn[8];
  #pragma unroll
  for (int n = 0; n < 8; ++n) wn[n] = tbl[96 + n];
  float SY = 0.f, CX = 0.f;
  for (int q = 0; q < 24; ++q) {
    const float csx = tbl[48 + q];
    const float ssy = tbl[72 + q];
    float e2 = 0.f;
    #pragma unroll
    for (int n = 0; n < 8; ++n) {
      const float tn = 0.375f * (float)(n + 1);
      float px = fmaf(-csx, tn, axl);
      float py = fmaf(-ssy, tn, ayl);
      int ix = (int)px, iy = (int)py;
      float fx = FRACTF(px), fy = FRACTF(py);
      float4 v = Qd[iy * TWX + ix];
      float s = fmaf(fx * fy, v.w, fmaf(fy, v.z, fmaf(fx, v.y, v.x)));
      e2 = fmaf(wn[n], s, e2);
    }
    float e = EXP2F(e2);
    SY = fmaf(e, tbl[24 + q], SY);
    CX = fmaf(e, tbl[q], CX);
  }
  const int* ti = (const int*)tbl;
  const int cbase = (ty + 1) * TWX + tx + 1;
  float a0 = 0.f, a1 = 0.f, a2 = 0.f, a3 = 0.f;
  if (ti[107] == 0) {
    #pragma unroll
    for (int t2 = 0; t2 < 8; ++t2) {
      a0 = fmaf(Sm[cbase + ti[140 + t2]], tbl[108 + t2], a0);
      a1 = fmaf(Sm[cbase + ti[148 + t2]], tbl[116 + t2], a1);
      a2 = fmaf(Sm[cbase + ti[156 + t2]], tbl[124 + t2], a2);
      a3 = fmaf(Sm[cbase + ti[164 + t2]], tbl[132 + t2], a3);
    }
  } else {
    for (int kj = 0; kj < 7; ++kj)
      for (int ki = 0; ki < 7; ++ki) {
        float s = Sm[(ty + 1 + kj) * TWX + (tx + 1 + ki)];
        int k = kj * 7 + ki;
        a0 = fmaf(s, Wb[k], a0); a1 = fmaf(s, Wb[49 + k], a1);
        a2 = fmaf(s, Wb[98 + k], a2); a3 = fmaf(s, Wb[147 + k], a3);
      }
  }
  const float TP  = 6.283185307179586f;
  const float PIF = 3.14159265358979323846f;
  const float HP  = 1.57079632679489661923f;
  float hat = atan2f(SY, CX);
  float r1 = hat + TP;
  r1 = (r1 >= TP) ? (r1 - TP) : r1;
  float theta = (r1 >= PIF) ? (r1 - PIF) : r1;
  const float irt2  = tbl[104];
  const float gamma = tbl[105];
  const float gainc = tbl[106];
  float dist[4];
  #pragma unroll
  for (int o = 0; o < 4; ++o) {
    float d = theta - cen[o] + HP;
    d -= (d >= PIF) ? PIF : 0.f;
    d += (d < 0.f) ? PIF : 0.f;
    dist[o] = fabsf(d - HP);
  }
  float mn = fminf(fminf(dist[0], dist[1]), fminf(dist[2], dist[3]));
  float m2 = mn * irt2;
  float eo[4], Z = 0.f;
  #pragma unroll
  for (int o = 0; o < 4; ++o) { eo[o] = EXP2F(fmaf(-irt2, dist[o], m2)); Z += eo[o]; }
  float invZ = 1.0f / Z;
  float sh[4], Zs = 0.f;
  #pragma unroll
  for (int o = 0; o < 4; ++o) {
    sh[o] = EXP2F(gamma * LOG2F(fmaf(eo[o], invZ, 1e-12f)));
    Zs += sh[o];
  }
  float wsi = 1.0f / (Zs + 1e-8f);
  float ov = (a0 * sh[0] + a1 * sh[1] + a2 * sh[2] + a3 * sh[3]) * wsi;
  out[((size_t)b * 512 + gj) * 512 + gi] = gainc * ov;
}

extern "C" void kernel_launch(void* const* d_in, const int* in_sizes, int n_in,
                              void* d_out, int out_size, void* d_ws, size_t ws_size,
                              hipStream_t stream) {
  const float* x    = (const float*)d_in[0];
  const float* gain = (const float*)d_in[1];
  const float* lrt  = (const float*)d_in[2];
  const float* rlg  = (const float*)d_in[3];
  const float* Wb   = (const float*)d_in[4];
  const float* cen  = (const float*)d_in[5];
  float* tbl = (float*)d_ws;

  gp_setup<<<1, 64, 0, stream>>>(gain, lrt, rlg, Wb, tbl);

  size_t need = 4096 + (size_t)8 * QIH * QIW * sizeof(float4);
  if (ws_size >= need) {
    float4* qimg = (float4*)((char*)d_ws + 4096);
    gp_quad<<<dim3((QIH + 63) / 64, QIH / 4, 8), dim3(256), 0, stream>>>(x, qimg);
    gp_main2<<<dim3(8192), dim3(256), 0, stream>>>(x, qimg, Wb, cen, tbl, (float*)d_out);
  } else {
    gp_main_fb<<<dim3(8, 128, 8), dim3(64, 4), 0, stream>>>(x, Wb, cen, tbl, (float*)d_out);
  }
}